// Round 8
// baseline (599.730 us; speedup 1.0000x reference)
//
#include <hip/hip_runtime.h>

namespace {

constexpr int N = 29;
constexpr int K = 6;
constexpr int D = 12;
constexpr int M = 32;
constexpr int EIN = 25;
constexpr int H1 = 50;
constexpr int NHID = 24;    // node hidden = 2*D
constexpr int HHID = 32;    // head hidden
constexpr int ODIM = 24;    // head out = 2*D
constexpr int NEDGE = N * K;   // 174
constexpr int MT = 11;         // M-tiles of 16 rows (176 >= 174)

typedef __attribute__((ext_vector_type(8))) short short8;
typedef __attribute__((ext_vector_type(4))) float f32x4;

__device__ __forceinline__ float sigmoidf_(float v) { return 1.0f / (1.0f + __expf(-v)); }
__device__ __forceinline__ float siluf_(float v) { return v * sigmoidf_(v); }
__device__ __forceinline__ ushort f2bf(float f) {      // fp32 -> bf16, RNE
  unsigned u = __float_as_uint(f);
  return (ushort)((u + 0x7FFFu + ((u >> 16) & 1u)) >> 16);
}

// MFMA fragment maps (mfma_f32_16x16x32_bf16, m89-verified C layout):
//   A[m][k]: m = lane&15,            k = (lane>>4)*8 + i   (i = 0..7)
//   B[k][n]: n = lane&15,            k = (lane>>4)*8 + i
//   C[m][n]: n = lane&15,            m = (lane>>4)*4 + reg (reg = 0..3)
__global__ __launch_bounds__(256) void arnet_fused(
    const float* __restrict__ x, const float* __restrict__ ctx,
    const float* __restrict__ ew1, const float* __restrict__ eb1,
    const float* __restrict__ ew2, const float* __restrict__ eb2,
    const float* __restrict__ gw, const float* __restrict__ gb,
    const float* __restrict__ nw1, const float* __restrict__ nb1,
    const float* __restrict__ nw2, const float* __restrict__ nb2,
    const float* __restrict__ hw1, const float* __restrict__ hb1,
    const float* __restrict__ hw2, const float* __restrict__ hb2,
    float* __restrict__ out)
{
  // edge-MLP weights as bf16 B-fragments, fragment-linear: [tile][lane][i]
  __shared__ __attribute__((aligned(16))) ushort s_w1f[4][64][8];     // GEMM1 B: [25->32 x 50->64]
  __shared__ __attribute__((aligned(16))) ushort s_w2f[2][2][64][8];  // GEMM2 B: [50->64 x 32]
  // node/head weights (fp32, broadcast-read)
  __shared__ float s_nw1[D + M][NHID];
  __shared__ float s_nb1[NHID];
  __shared__ float s_nw2[NHID][D];
  __shared__ float s_nb2[D];
  __shared__ float s_hw1[D][HHID];
  __shared__ float s_hb1[HHID];
  __shared__ float s_hw2[HHID][ODIM];
  __shared__ float s_hb2[ODIM];
  // per-batch state
  __shared__ float s_ctx[N][4];
  __shared__ __attribute__((aligned(16))) float s_feat[N][D];  // 48B rows, float4-aligned
  __shared__ float s_dist[N][33];    // +1 pad: conflict-free column scans
  __shared__ int   s_nbhd[N][K];
  __shared__ float s_rdist[N][K];
  __shared__ float s_mi[N][33];      // fp32 accum of gated messages (+1 pad)
  __shared__ __attribute__((aligned(16))) ushort s_H[4][16][72];  // per-wave H scratch (144B rows)
  __shared__ float s_nh1[N][NHID];
  __shared__ float s_nout[N][D];
  __shared__ float s_pool[D];
  __shared__ float s_hid[HHID];
  __shared__ float s_res[ODIM];

  const int tid = threadIdx.x;
  const int b = blockIdx.x;

  // ---- stage edge-MLP weights as MFMA B-fragments (bf16) ----
  {
    const int l = tid & 63, kb = l >> 4;
    const int nt = tid >> 6;                       // 0..3 -> W1 n-tile
    const int n1 = (l & 15) + 16 * nt;
    #pragma unroll
    for (int i = 0; i < 8; ++i) {
      const int k = kb * 8 + i;
      s_w1f[nt][l][i] = f2bf((k < EIN && n1 < H1) ? ew1[k * H1 + n1] : 0.0f);
    }
    const int nt2 = tid >> 7, kt = (tid >> 6) & 1; // 0..1 x 0..1 -> W2 (n-tile, k-tile)
    const int n2 = (l & 15) + 16 * nt2;
    #pragma unroll
    for (int i = 0; i < 8; ++i) {
      const int k = kt * 32 + kb * 8 + i;
      s_w2f[nt2][kt][l][i] = f2bf((k < H1) ? ew2[k * M + n2] : 0.0f);
    }
  }

  // ---- stage node/head weights ----
  for (int i = tid; i < (D + M) * NHID; i += 256) s_nw1[i / NHID][i % NHID] = nw1[i];
  for (int i = tid; i < NHID; i += 256) s_nb1[i] = nb1[i];
  for (int i = tid; i < NHID * D; i += 256) s_nw2[i / D][i % D] = nw2[i];
  for (int i = tid; i < D; i += 256) s_nb2[i] = nb2[i];
  for (int i = tid; i < D * HHID; i += 256) s_hw1[i / HHID][i % HHID] = hw1[i];
  for (int i = tid; i < HHID; i += 256) s_hb1[i] = hb1[i];
  for (int i = tid; i < HHID * ODIM; i += 256) s_hw2[i / ODIM][i % ODIM] = hw2[i];
  for (int i = tid; i < ODIM; i += 256) s_hb2[i] = hb2[i];

  // ---- stage per-batch inputs ----
  for (int i = tid; i < N * D; i += 256) {
    int r = i / D, c = i - r * D;
    s_feat[r][c] = x[(size_t)b * (N * 6) + r * 6 + (c % 6)];   // feats = concat([x,x])
  }
  for (int i = tid; i < N * 3; i += 256)
    s_ctx[i / 3][i % 3] = ctx[(size_t)b * (N * 3) + i];
  for (int i = tid; i < N * 32; i += 256) s_mi[i >> 5][i & 31] = 0.0f;
  __syncthreads();

  // ---- pairwise squared distances ----
  for (int i = tid; i < N * N; i += 256) {
    int r = i / N, c = i - r * N;
    float dx = s_ctx[r][0] - s_ctx[c][0];
    float dy = s_ctx[r][1] - s_ctx[c][1];
    float dz = s_ctx[r][2] - s_ctx[c][2];
    s_dist[r][c] = dx * dx + dy * dy + dz * dz;
  }
  __syncthreads();

  // ---- kNN: wave-parallel argmin; tie -> lower index (stable top_k) ----
  {
    const int g2 = tid >> 5, t2 = tid & 31;
    for (int r = g2; r < N; r += 8) {
      float v = (t2 < N) ? s_dist[r][t2] : 3.4e38f;
      const int myj = t2;
      #pragma unroll 1
      for (int k = 0; k < K; ++k) {
        float bv = v; int bi = myj;
        #pragma unroll
        for (int off = 16; off > 0; off >>= 1) {
          float ov = __shfl_xor(bv, off, 32);
          int oi = __shfl_xor(bi, off, 32);
          if (ov < bv || (ov == bv && oi < bi)) { bv = ov; bi = oi; }
        }
        if (t2 == 0) { s_nbhd[r][k] = bi; s_rdist[r][k] = bv; }
        if (myj == bi) v = 3.4e38f;
      }
    }
  }
  __syncthreads();

  // ---- edge MLP via MFMA: 11 M-tiles over 4 waves; no block barriers inside ----
  const int w = tid >> 6;
  const int l = tid & 63;
  const int lr = l & 15;    // A/C: row-in-tile (A) / channel (C-col)
  const int lk = l >> 4;    // k-block (A/B) / row-group (C)

  short8 w1b[4], w2b[2][2];
  #pragma unroll
  for (int nt = 0; nt < 4; ++nt) w1b[nt] = *(const short8*)&s_w1f[nt][l][0];
  #pragma unroll
  for (int nt2 = 0; nt2 < 2; ++nt2)
    #pragma unroll
    for (int kt = 0; kt < 2; ++kt) w2b[nt2][kt] = *(const short8*)&s_w2f[nt2][kt][l][0];

  float bias1[4], bias2[2], gwr[2];
  #pragma unroll
  for (int nt = 0; nt < 4; ++nt) { int n = lr + 16 * nt; bias1[nt] = (n < H1) ? eb1[n] : 0.0f; }
  #pragma unroll
  for (int nt2 = 0; nt2 < 2; ++nt2) { int n = lr + 16 * nt2; bias2[nt2] = eb2[n]; gwr[nt2] = gw[n]; }
  const float gbr = gb[0];

  #pragma unroll 1
  for (int mt = w; mt < MT; mt += 4) {
    const int m0 = mt * 16;
    // --- build GEMM1 A-fragment (edge_in row e = m0+lr, k = lk*8 + i) ---
    const int e = m0 + lr;
    const bool ev = (e < NEDGE);
    const int ei = ev ? (e / K) : 0;
    const int kk = ev ? (e - ei * K) : 0;
    const int ej = s_nbhd[ei][kk];
    const float rdv = s_rdist[ei][kk];

    float fv[8];
    if (lk == 0) {            // cols 0-7: feats_i[0..7]
      float4 a = *(const float4*)&s_feat[ei][0];
      float4 c = *(const float4*)&s_feat[ei][4];
      fv[0]=a.x; fv[1]=a.y; fv[2]=a.z; fv[3]=a.w; fv[4]=c.x; fv[5]=c.y; fv[6]=c.z; fv[7]=c.w;
    } else if (lk == 1) {     // cols 8-15: feats_i[8..11] + feats_j[0..3]
      float4 a = *(const float4*)&s_feat[ei][8];
      float4 c = *(const float4*)&s_feat[ej][0];
      fv[0]=a.x; fv[1]=a.y; fv[2]=a.z; fv[3]=a.w; fv[4]=c.x; fv[5]=c.y; fv[6]=c.z; fv[7]=c.w;
    } else if (lk == 2) {     // cols 16-23: feats_j[4..11]
      float4 a = *(const float4*)&s_feat[ej][4];
      float4 c = *(const float4*)&s_feat[ej][8];
      fv[0]=a.x; fv[1]=a.y; fv[2]=a.z; fv[3]=a.w; fv[4]=c.x; fv[5]=c.y; fv[6]=c.z; fv[7]=c.w;
    } else {                  // col 24: rel_dist; 25-31: zero pad
      fv[0]=rdv; fv[1]=0.f; fv[2]=0.f; fv[3]=0.f; fv[4]=0.f; fv[5]=0.f; fv[6]=0.f; fv[7]=0.f;
    }
    short8 a1;
    #pragma unroll
    for (int i = 0; i < 8; ++i) a1[i] = ev ? (short)f2bf(fv[i]) : (short)0;

    // --- GEMM1: H-tile = silu(E @ W1 + b1) -> per-wave LDS scratch (bf16) ---
    #pragma unroll
    for (int nt = 0; nt < 4; ++nt) {
      f32x4 acc = __builtin_amdgcn_mfma_f32_16x16x32_bf16(
          a1, w1b[nt], (f32x4){0.f, 0.f, 0.f, 0.f}, 0, 0, 0);
      #pragma unroll
      for (int r = 0; r < 4; ++r)
        s_H[w][lk * 4 + r][lr + 16 * nt] = f2bf(siluf_(acc[r] + bias1[nt]));
    }

    // --- GEMM2: Mm-tile = silu(H @ W2 + b2); H rows re-read in A layout ---
    f32x4 acc2[2] = { (f32x4){0.f,0.f,0.f,0.f}, (f32x4){0.f,0.f,0.f,0.f} };
    #pragma unroll
    for (int kt = 0; kt < 2; ++kt) {
      short8 a2 = *(const short8*)&s_H[w][lr][kt * 32 + lk * 8];
      #pragma unroll
      for (int nt2 = 0; nt2 < 2; ++nt2)
        acc2[nt2] = __builtin_amdgcn_mfma_f32_16x16x32_bf16(a2, w2b[nt2][kt], acc2[nt2], 0, 0, 0);
    }

    // --- soft edge gate + scatter-sum (rows er = m0 + lk*4 + r) ---
    float sv[2][4], part[4];
    #pragma unroll
    for (int r = 0; r < 4; ++r) part[r] = 0.f;
    #pragma unroll
    for (int nt2 = 0; nt2 < 2; ++nt2)
      #pragma unroll
      for (int r = 0; r < 4; ++r) {
        sv[nt2][r] = siluf_(acc2[nt2][r] + bias2[nt2]);
        part[r] = fmaf(sv[nt2][r], gwr[nt2], part[r]);
      }
    #pragma unroll
    for (int r = 0; r < 4; ++r) {
      #pragma unroll
      for (int off = 1; off < 16; off <<= 1)
        part[r] += __shfl_xor(part[r], off);   // sum over the 16 lanes = channels 0..31
    }
    #pragma unroll
    for (int r = 0; r < 4; ++r) {
      const int er = m0 + lk * 4 + r;
      if (er < NEDGE) {
        const float gate = sigmoidf_(part[r] + gbr);
        const int ni = er / K;
        atomicAdd(&s_mi[ni][lr],      sv[0][r] * gate);
        atomicAdd(&s_mi[ni][lr + 16], sv[1][r] * gate);
      }
    }
  }
  __syncthreads();

  // ---- node MLP (+ residual), fp32 ----
  for (int u = tid; u < N * NHID; u += 256) {
    int i = u / NHID, o = u - i * NHID;
    float a = s_nb1[o];
    #pragma unroll
    for (int c = 0; c < D; ++c) a = fmaf(s_feat[i][c], s_nw1[c][o], a);
    #pragma unroll
    for (int c = 0; c < M; ++c) a = fmaf(s_mi[i][c], s_nw1[D + c][o], a);
    s_nh1[i][o] = siluf_(a);
  }
  __syncthreads();
  for (int u = tid; u < N * D; u += 256) {
    int i = u / D, o = u - i * D;
    float a = s_nb2[o];
    #pragma unroll
    for (int h = 0; h < NHID; ++h) a = fmaf(s_nh1[i][h], s_nw2[h][o], a);
    s_nout[i][o] = a + s_feat[i][o];
  }
  __syncthreads();

  // ---- masked mean pool (mask all-ones -> /29) ----
  if (tid < D) {
    float a = 0.0f;
    for (int i = 0; i < N; ++i) a += s_nout[i][tid];
    s_pool[tid] = a / 29.0f;
  }
  __syncthreads();

  // ---- head MLP ----
  if (tid < HHID) {
    float a = s_hb1[tid];
    #pragma unroll
    for (int c = 0; c < D; ++c) a = fmaf(s_pool[c], s_hw1[c][tid], a);
    s_hid[tid] = fmaxf(a, 0.0f);
  }
  __syncthreads();
  if (tid < ODIM) {
    float a = s_hb2[tid];
    #pragma unroll
    for (int h = 0; h < HHID; ++h) a = fmaf(s_hid[h], s_hw2[h][tid], a);
    s_res[tid] = a;
  }
  __syncthreads();

  // ---- write [29][12]: rows 0..1 = head out, rows 2..28 = zero padding ----
  float* ob = out + (size_t)b * (N * D);
  for (int i = tid; i < N * D; i += 256) ob[i] = (i < ODIM) ? s_res[i] : 0.0f;
}

} // namespace

extern "C" void kernel_launch(void* const* d_in, const int* in_sizes, int n_in,
                              void* d_out, int out_size, void* d_ws, size_t ws_size,
                              hipStream_t stream) {
  const float* x   = (const float*)d_in[0];
  const float* ctx = (const float*)d_in[1];
  // d_in[2] = mask: constant all-ones in this problem -> mathematically a no-op
  const float* ew1 = (const float*)d_in[3];
  const float* eb1 = (const float*)d_in[4];
  const float* ew2 = (const float*)d_in[5];
  const float* eb2 = (const float*)d_in[6];
  const float* gw  = (const float*)d_in[7];
  const float* gb  = (const float*)d_in[8];
  const float* nw1 = (const float*)d_in[9];
  const float* nb1 = (const float*)d_in[10];
  const float* nw2 = (const float*)d_in[11];
  const float* nb2 = (const float*)d_in[12];
  const float* hw1 = (const float*)d_in[13];
  const float* hb1 = (const float*)d_in[14];
  const float* hw2 = (const float*)d_in[15];
  const float* hb2 = (const float*)d_in[16];
  float* o = (float*)d_out;

  hipLaunchKernelGGL(arnet_fused, dim3(8192), dim3(256), 0, stream,
                     x, ctx, ew1, eb1, ew2, eb2, gw, gb, nw1, nb1, nw2, nb2,
                     hw1, hb1, hw2, hb2, o);
}

// Round 11
// 496.580 us; speedup vs baseline: 1.2077x; 1.2077x over previous
//
#include <hip/hip_runtime.h>

namespace {

constexpr int N = 29;
constexpr int K = 6;
constexpr int D = 12;
constexpr int M = 32;
constexpr int H1 = 50;
constexpr int NHID = 24;    // node hidden = 2*D
constexpr int HHID = 32;    // head hidden
constexpr int ODIM = 24;    // head out = 2*D
constexpr int NITER = 4;    // ceil(29 nodes / 8 groups)

__device__ __forceinline__ float sigmoidf_(float v) { return 1.0f / (1.0f + __expf(-v)); }
__device__ __forceinline__ float siluf_(float v) { return v * sigmoidf_(v); }
__device__ __forceinline__ float getq(const float4& f, int q) {
  switch (q) { case 0: return f.x; case 1: return f.y; case 2: return f.z; default: return f.w; }
}

// r7 structure (node-per-group edge phase, LDS-streamed weights) + LDS diet:
// phase-disjoint buffers {dist | h1 | nh1+nout+head-weights+tail} share one
// union region; head weights staged late. 48.6 -> 33.7 KB => 4 blocks/CU.
__global__ __launch_bounds__(256) void arnet_fused(
    const float* __restrict__ x, const float* __restrict__ ctx,
    const float* __restrict__ ew1, const float* __restrict__ eb1,
    const float* __restrict__ ew2, const float* __restrict__ eb2,
    const float* __restrict__ gw, const float* __restrict__ gb,
    const float* __restrict__ nw1, const float* __restrict__ nb1,
    const float* __restrict__ nw2, const float* __restrict__ nb2,
    const float* __restrict__ hw1, const float* __restrict__ hb1,
    const float* __restrict__ hw2, const float* __restrict__ hb2,
    float* __restrict__ out)
{
  // edge-MLP weights (LDS-resident, conflict-benign layouts)
  __shared__ float s_w1[25][52];    // [c][h] row-padded; lane t reads float2 at [c][2t]
  __shared__ float s_b1[52];
  __shared__ float s_w2p[25][64];   // pair-packed: [u][2t+par] = e_w2[2u+par][t]
  __shared__ float s_b2[M];
  __shared__ float s_gw[M];
  __shared__ float s_gb;
  // node weights
  __shared__ float s_nw1[D + M][NHID];
  __shared__ float s_nb1[NHID];
  __shared__ float s_nw2[NHID][D];
  __shared__ float s_nb2[D];
  // persistent per-batch state
  __shared__ float s_ctx[N][4];
  __shared__ __attribute__((aligned(16))) float s_feat[N][D];  // 48B rows, float4-aligned
  __shared__ int   s_nbhd[N][K];
  __shared__ float s_rdist[N][K];
  __shared__ float s_mi[N][M];
  // phase-union region (9984 B), barriers separate all uses:
  //   kNN:  dist[29][33]                    (957 f)
  //   edge: h1[8][6][52]                    (2496 f)
  //   node: nh1[29][24] + nout[29][12]      (696 + 348 f)
  //   tail: hw1/hb1/hw2/hb2/pool/hid/res    (@1044.. 2320 f total)
  __shared__ __attribute__((aligned(16))) float u_buf[2496];

  float (*s_dist)[33]   = (float(*)[33])u_buf;
  float (*s_h1)[K][52]  = (float(*)[K][52])u_buf;
  float (*s_nh1)[NHID]  = (float(*)[NHID])u_buf;
  float (*s_nout)[D]    = (float(*)[D])(u_buf + 696);
  float (*s_hw1)[HHID]  = (float(*)[HHID])(u_buf + 1044);
  float *s_hb1          = u_buf + 1428;
  float (*s_hw2)[ODIM]  = (float(*)[ODIM])(u_buf + 1460);
  float *s_hb2          = u_buf + 2228;
  float *s_pool         = u_buf + 2252;
  float *s_hid          = u_buf + 2264;
  float *s_res          = u_buf + 2296;

  const int tid = threadIdx.x;
  const int b = blockIdx.x;
  const int g = tid >> 5, t = tid & 31;
  const int tt = (t < 25) ? t : 24;    // clamp for layer-1 reads (lanes 25..31 dup)

  // ---- stage edge-MLP weights ----
  for (int i = tid; i < 25 * H1; i += 256) s_w1[i / H1][i % H1] = ew1[i];
  for (int i = tid; i < H1; i += 256) s_b1[i] = eb1[i];
  for (int i = tid; i < 25 * 64; i += 256) {
    int u = i >> 6, c = i & 63, tc = c >> 1, par = c & 1;
    s_w2p[u][c] = ew2[(2 * u + par) * M + tc];
  }
  for (int i = tid; i < M; i += 256) { s_b2[i] = eb2[i]; s_gw[i] = gw[i]; }
  if (tid == 0) s_gb = gb[0];

  // ---- stage node weights ----
  for (int i = tid; i < (D + M) * NHID; i += 256) s_nw1[i / NHID][i % NHID] = nw1[i];
  for (int i = tid; i < NHID; i += 256) s_nb1[i] = nb1[i];
  for (int i = tid; i < NHID * D; i += 256) s_nw2[i / D][i % D] = nw2[i];
  for (int i = tid; i < D; i += 256) s_nb2[i] = nb2[i];

  // ---- stage per-batch inputs ----
  for (int i = tid; i < N * D; i += 256) {
    int r = i / D, c = i - r * D;
    s_feat[r][c] = x[(size_t)b * (N * 6) + r * 6 + (c % 6)];   // feats = concat([x,x])
  }
  for (int i = tid; i < N * 3; i += 256)
    s_ctx[i / 3][i % 3] = ctx[(size_t)b * (N * 3) + i];
  __syncthreads();

  // ---- pairwise squared distances (into union: dist) ----
  for (int i = tid; i < N * N; i += 256) {
    int r = i / N, c = i - r * N;
    float dx = s_ctx[r][0] - s_ctx[c][0];
    float dy = s_ctx[r][1] - s_ctx[c][1];
    float dz = s_ctx[r][2] - s_ctx[c][2];
    s_dist[r][c] = dx * dx + dy * dy + dz * dz;
  }
  __syncthreads();

  // ---- kNN: wave-parallel argmin; tie -> lower index (stable top_k) ----
  for (int r = g; r < N; r += 8) {
    float v = (t < N) ? s_dist[r][t] : 3.4e38f;
    const int myj = t;
    #pragma unroll 1
    for (int k = 0; k < K; ++k) {
      float bv = v; int bi = myj;
      #pragma unroll
      for (int off = 16; off > 0; off >>= 1) {
        float ov = __shfl_xor(bv, off, 32);
        int oi = __shfl_xor(bi, off, 32);
        if (ov < bv || (ov == bv && oi < bi)) { bv = ov; bi = oi; }
      }
      if (t == 0) { s_nbhd[r][k] = bi; s_rdist[r][k] = bv; }
      if (myj == bi) v = 3.4e38f;
    }
  }
  __syncthreads();   // dist dead; union becomes h1

  // ---- edge phase: group g owns node i = it*8+g; its 6 edges together.
  // All LDS producer/consumer pairs are same-wave -> no block barriers.
  const float2 b1v = *(const float2*)&s_b1[2 * tt];
  const float b2v = s_b2[t];
  const float gwr = s_gw[t];
  const float gbr = s_gb;

  #pragma unroll 1
  for (int it2 = 0; it2 < NITER; ++it2) {
    const int i = it2 * 8 + g;
    if (i < N) {
      int nb[K]; float rdv[K];
      #pragma unroll
      for (int k = 0; k < K; ++k) { nb[k] = s_nbhd[i][k]; rdv[k] = s_rdist[i][k]; }

      // layer-1, feats_i half: identical for all 6 edges -> compute once
      float pa0 = b1v.x, pa1 = b1v.y;
      #pragma unroll
      for (int p = 0; p < 3; ++p) {
        float4 f = *(const float4*)&s_feat[i][4 * p];
        #pragma unroll
        for (int q = 0; q < 4; ++q) {
          float2 w = *(const float2*)&s_w1[4 * p + q][2 * tt];
          float fv = getq(f, q);
          pa0 = fmaf(fv, w.x, pa0); pa1 = fmaf(fv, w.y, pa1);
        }
      }
      float a0[K], a1[K];
      #pragma unroll
      for (int k = 0; k < K; ++k) { a0[k] = pa0; a1[k] = pa1; }

      // layer-1, feats_j half: per-edge
      #pragma unroll
      for (int p = 0; p < 3; ++p) {
        float4 fj[K];
        #pragma unroll
        for (int k = 0; k < K; ++k) fj[k] = *(const float4*)&s_feat[nb[k]][4 * p];
        #pragma unroll
        for (int q = 0; q < 4; ++q) {
          float2 w = *(const float2*)&s_w1[12 + 4 * p + q][2 * tt];
          #pragma unroll
          for (int k = 0; k < K; ++k) {
            float fv = getq(fj[k], q);
            a0[k] = fmaf(fv, w.x, a0[k]); a1[k] = fmaf(fv, w.y, a1[k]);
          }
        }
      }
      { // rel_dist channel
        float2 w = *(const float2*)&s_w1[24][2 * tt];
        #pragma unroll
        for (int k = 0; k < K; ++k) {
          a0[k] = fmaf(rdv[k], w.x, a0[k]); a1[k] = fmaf(rdv[k], w.y, a1[k]);
        }
      }
      if (t < 25) {
        #pragma unroll
        for (int k = 0; k < K; ++k)
          *(float2*)&s_h1[g][k][2 * t] = make_float2(siluf_(a0[k]), siluf_(a1[k]));
      }

      // layer-2: lane t = output channel t; w2 pair-reads amortized over 6 edges
      float mc[K];
      #pragma unroll
      for (int k = 0; k < K; ++k) mc[k] = b2v;
      #pragma unroll
      for (int hv = 0; hv < 12; ++hv) {
        float2 wa = *(const float2*)&s_w2p[2 * hv][2 * t];
        float2 wb = *(const float2*)&s_w2p[2 * hv + 1][2 * t];
        #pragma unroll
        for (int k = 0; k < K; ++k) {
          float4 h = *(const float4*)&s_h1[g][k][4 * hv];
          mc[k] = fmaf(h.x, wa.x, mc[k]); mc[k] = fmaf(h.y, wa.y, mc[k]);
          mc[k] = fmaf(h.z, wb.x, mc[k]); mc[k] = fmaf(h.w, wb.y, mc[k]);
        }
      }
      { // tail h = 48,49
        float2 w = *(const float2*)&s_w2p[24][2 * t];
        #pragma unroll
        for (int k = 0; k < K; ++k) {
          float2 h = *(const float2*)&s_h1[g][k][48];
          mc[k] = fmaf(h.x, w.x, mc[k]); mc[k] = fmaf(h.y, w.y, mc[k]);
        }
      }
      #pragma unroll
      for (int k = 0; k < K; ++k) mc[k] = siluf_(mc[k]);

      // soft edge gate + in-register scatter-sum (node owned by this group)
      float acc = 0.0f;
      #pragma unroll
      for (int k = 0; k < K; ++k) {
        float p2 = mc[k] * gwr;
        #pragma unroll
        for (int off = 16; off > 0; off >>= 1) p2 += __shfl_xor(p2, off, 32);
        acc = fmaf(mc[k], sigmoidf_(p2 + gbr), acc);
      }
      s_mi[i][t] = acc;     // plain store: exactly one group writes node i
    }
  }
  __syncthreads();   // h1 dead; union becomes nh1/nout

  // ---- node MLP (+ residual) ----
  for (int u = tid; u < N * NHID; u += 256) {
    int i = u / NHID, o = u - i * NHID;
    float a = s_nb1[o];
    #pragma unroll
    for (int c = 0; c < D; ++c) a = fmaf(s_feat[i][c], s_nw1[c][o], a);
    #pragma unroll
    for (int c = 0; c < M; ++c) a = fmaf(s_mi[i][c], s_nw1[D + c][o], a);
    s_nh1[i][o] = siluf_(a);
  }
  __syncthreads();
  for (int u = tid; u < N * D; u += 256) {
    int i = u / D, o = u - i * D;
    float a = s_nb2[o];
    #pragma unroll
    for (int h = 0; h < NHID; ++h) a = fmaf(s_nh1[i][h], s_nw2[h][o], a);
    s_nout[i][o] = a + s_feat[i][o];
  }
  __syncthreads();   // nh1 dead; tail region (u_buf+1044..) free

  // ---- masked mean pool (/29) + LATE head-weight staging (parallel) ----
  if (tid < D) {
    float a = 0.0f;
    for (int i = 0; i < N; ++i) a += s_nout[i][tid];
    s_pool[tid] = a / 29.0f;
  }
  for (int i = tid; i < D * HHID; i += 256) s_hw1[i / HHID][i % HHID] = hw1[i];
  for (int i = tid; i < HHID; i += 256) s_hb1[i] = hb1[i];
  for (int i = tid; i < HHID * ODIM; i += 256) s_hw2[i / ODIM][i % ODIM] = hw2[i];
  for (int i = tid; i < ODIM; i += 256) s_hb2[i] = hb2[i];
  __syncthreads();

  // ---- head MLP ----
  if (tid < HHID) {
    float a = s_hb1[tid];
    #pragma unroll
    for (int c = 0; c < D; ++c) a = fmaf(s_pool[c], s_hw1[c][tid], a);
    s_hid[tid] = fmaxf(a, 0.0f);
  }
  __syncthreads();
  if (tid < ODIM) {
    float a = s_hb2[tid];
    #pragma unroll
    for (int h = 0; h < HHID; ++h) a = fmaf(s_hid[h], s_hw2[h][tid], a);
    s_res[tid] = a;
  }
  __syncthreads();

  // ---- write [29][12]: rows 0..1 = head out, rows 2..28 = zero padding ----
  float* ob = out + (size_t)b * (N * D);
  for (int i = tid; i < N * D; i += 256) ob[i] = (i < ODIM) ? s_res[i] : 0.0f;
}

} // namespace

extern "C" void kernel_launch(void* const* d_in, const int* in_sizes, int n_in,
                              void* d_out, int out_size, void* d_ws, size_t ws_size,
                              hipStream_t stream) {
  const float* x   = (const float*)d_in[0];
  const float* ctx = (const float*)d_in[1];
  // d_in[2] = mask: constant all-ones in this problem -> mathematically a no-op
  const float* ew1 = (const float*)d_in[3];
  const float* eb1 = (const float*)d_in[4];
  const float* ew2 = (const float*)d_in[5];
  const float* eb2 = (const float*)d_in[6];
  const float* gw  = (const float*)d_in[7];
  const float* gb  = (const float*)d_in[8];
  const float* nw1 = (const float*)d_in[9];
  const float* nb1 = (const float*)d_in[10];
  const float* nw2 = (const float*)d_in[11];
  const float* nb2 = (const float*)d_in[12];
  const float* hw1 = (const float*)d_in[13];
  const float* hb1 = (const float*)d_in[14];
  const float* hw2 = (const float*)d_in[15];
  const float* hb2 = (const float*)d_in[16];
  float* o = (float*)d_out;

  hipLaunchKernelGGL(arnet_fused, dim3(8192), dim3(256), 0, stream,
                     x, ctx, ew1, eb1, ew2, eb2, gw, gb, nw1, nb1, nw2, nb2,
                     hw1, hb1, hw2, hb2, o);
}

// Round 12
// 439.887 us; speedup vs baseline: 1.3634x; 1.1289x over previous
//
#include <hip/hip_runtime.h>

namespace {

constexpr int N = 29;
constexpr int K = 6;
constexpr int D = 12;
constexpr int M = 32;
constexpr int H1 = 50;
constexpr int NHID = 24;    // node hidden = 2*D
constexpr int HHID = 32;    // head hidden
constexpr int ODIM = 24;    // head out = 2*D
constexpr int NITER = 4;    // ceil(29 nodes / 8 groups)

typedef __attribute__((ext_vector_type(2))) float v2f;
typedef __attribute__((ext_vector_type(4))) float v4f;

__device__ __forceinline__ float sigmoidf_(float v) { return 1.0f / (1.0f + __expf(-v)); }
__device__ __forceinline__ float siluf_(float v) { return v * sigmoidf_(v); }
__device__ __forceinline__ v2f pkfma(v2f a, v2f b, v2f c) {
  return __builtin_elementwise_fma(a, b, c);     // -> v_pk_fma_f32 (VOP3P, 2 FMA/instr)
}
__device__ __forceinline__ float getq(const v4f& f, int q) {
  switch (q) { case 0: return f.x; case 1: return f.y; case 2: return f.z; default: return f.w; }
}

// r11 structure (node-per-group edge phase, LDS union) + packed-fp32 edge
// math: layer-1 packs the lane's two hidden channels, layer-2 packs even/odd
// hidden partial sums. All packed operands are naturally adjacent registers.
__global__ __launch_bounds__(256) void arnet_fused(
    const float* __restrict__ x, const float* __restrict__ ctx,
    const float* __restrict__ ew1, const float* __restrict__ eb1,
    const float* __restrict__ ew2, const float* __restrict__ eb2,
    const float* __restrict__ gw, const float* __restrict__ gb,
    const float* __restrict__ nw1, const float* __restrict__ nb1,
    const float* __restrict__ nw2, const float* __restrict__ nb2,
    const float* __restrict__ hw1, const float* __restrict__ hb1,
    const float* __restrict__ hw2, const float* __restrict__ hb2,
    float* __restrict__ out)
{
  // edge-MLP weights (LDS-resident, conflict-benign layouts)
  __shared__ float s_w1[25][52];    // [c][h] row-padded; lane t reads float2 at [c][2t]
  __shared__ float s_b1[52];
  __shared__ float s_w2p[25][64];   // pair-packed: [u][2t+par] = e_w2[2u+par][t]
  __shared__ float s_b2[M];
  __shared__ float s_gw[M];
  __shared__ float s_gb;
  // node weights
  __shared__ float s_nw1[D + M][NHID];
  __shared__ float s_nb1[NHID];
  __shared__ float s_nw2[NHID][D];
  __shared__ float s_nb2[D];
  // persistent per-batch state
  __shared__ float s_ctx[N][4];
  __shared__ __attribute__((aligned(16))) float s_feat[N][D];  // 48B rows, float4-aligned
  __shared__ int   s_nbhd[N][K];
  __shared__ float s_rdist[N][K];
  __shared__ float s_mi[N][M];
  // phase-union region (9984 B), barriers separate all uses:
  //   kNN:  dist[29][33] | edge: h1[8][6][52] | node: nh1+nout | tail: head W
  __shared__ __attribute__((aligned(16))) float u_buf[2496];

  float (*s_dist)[33]   = (float(*)[33])u_buf;
  float (*s_h1)[K][52]  = (float(*)[K][52])u_buf;
  float (*s_nh1)[NHID]  = (float(*)[NHID])u_buf;
  float (*s_nout)[D]    = (float(*)[D])(u_buf + 696);
  float (*s_hw1)[HHID]  = (float(*)[HHID])(u_buf + 1044);
  float *s_hb1          = u_buf + 1428;
  float (*s_hw2)[ODIM]  = (float(*)[ODIM])(u_buf + 1460);
  float *s_hb2          = u_buf + 2228;
  float *s_pool         = u_buf + 2252;
  float *s_hid          = u_buf + 2264;
  float *s_res          = u_buf + 2296;

  const int tid = threadIdx.x;
  const int b = blockIdx.x;
  const int g = tid >> 5, t = tid & 31;
  const int tt = (t < 25) ? t : 24;    // clamp for layer-1 reads (lanes 25..31 dup)

  // ---- stage edge-MLP weights ----
  for (int i = tid; i < 25 * H1; i += 256) s_w1[i / H1][i % H1] = ew1[i];
  for (int i = tid; i < H1; i += 256) s_b1[i] = eb1[i];
  for (int i = tid; i < 25 * 64; i += 256) {
    int u = i >> 6, c = i & 63, tc = c >> 1, par = c & 1;
    s_w2p[u][c] = ew2[(2 * u + par) * M + tc];
  }
  for (int i = tid; i < M; i += 256) { s_b2[i] = eb2[i]; s_gw[i] = gw[i]; }
  if (tid == 0) s_gb = gb[0];

  // ---- stage node weights ----
  for (int i = tid; i < (D + M) * NHID; i += 256) s_nw1[i / NHID][i % NHID] = nw1[i];
  for (int i = tid; i < NHID; i += 256) s_nb1[i] = nb1[i];
  for (int i = tid; i < NHID * D; i += 256) s_nw2[i / D][i % D] = nw2[i];
  for (int i = tid; i < D; i += 256) s_nb2[i] = nb2[i];

  // ---- stage per-batch inputs ----
  for (int i = tid; i < N * D; i += 256) {
    int r = i / D, c = i - r * D;
    s_feat[r][c] = x[(size_t)b * (N * 6) + r * 6 + (c % 6)];   // feats = concat([x,x])
  }
  for (int i = tid; i < N * 3; i += 256)
    s_ctx[i / 3][i % 3] = ctx[(size_t)b * (N * 3) + i];
  __syncthreads();

  // ---- pairwise squared distances (into union: dist) ----
  for (int i = tid; i < N * N; i += 256) {
    int r = i / N, c = i - r * N;
    float dx = s_ctx[r][0] - s_ctx[c][0];
    float dy = s_ctx[r][1] - s_ctx[c][1];
    float dz = s_ctx[r][2] - s_ctx[c][2];
    s_dist[r][c] = dx * dx + dy * dy + dz * dz;
  }
  __syncthreads();

  // ---- kNN: wave-parallel argmin; tie -> lower index (stable top_k) ----
  for (int r = g; r < N; r += 8) {
    float v = (t < N) ? s_dist[r][t] : 3.4e38f;
    const int myj = t;
    #pragma unroll 1
    for (int k = 0; k < K; ++k) {
      float bv = v; int bi = myj;
      #pragma unroll
      for (int off = 16; off > 0; off >>= 1) {
        float ov = __shfl_xor(bv, off, 32);
        int oi = __shfl_xor(bi, off, 32);
        if (ov < bv || (ov == bv && oi < bi)) { bv = ov; bi = oi; }
      }
      if (t == 0) { s_nbhd[r][k] = bi; s_rdist[r][k] = bv; }
      if (myj == bi) v = 3.4e38f;
    }
  }
  __syncthreads();   // dist dead; union becomes h1

  // ---- edge phase: group g owns node i = it*8+g; its 6 edges together.
  // All LDS producer/consumer pairs are same-wave -> no block barriers.
  const v2f b1p = *(const v2f*)&s_b1[2 * tt];
  const float b2v = s_b2[t];
  const float gwr = s_gw[t];
  const float gbr = s_gb;

  #pragma unroll 1
  for (int it2 = 0; it2 < NITER; ++it2) {
    const int i = it2 * 8 + g;
    if (i < N) {
      int nb[K]; float rdv[K];
      #pragma unroll
      for (int k = 0; k < K; ++k) { nb[k] = s_nbhd[i][k]; rdv[k] = s_rdist[i][k]; }

      // layer-1, feats_i half (packed): a01 = (hidden 2t, hidden 2t+1)
      v2f pa = b1p;
      #pragma unroll
      for (int p = 0; p < 3; ++p) {
        v4f f = *(const v4f*)&s_feat[i][4 * p];
        #pragma unroll
        for (int q = 0; q < 4; ++q) {
          v2f w = *(const v2f*)&s_w1[4 * p + q][2 * tt];
          float fv = getq(f, q);
          pa = pkfma((v2f){fv, fv}, w, pa);
        }
      }
      v2f a01[K];
      #pragma unroll
      for (int k = 0; k < K; ++k) a01[k] = pa;

      // layer-1, feats_j half: per-edge (packed)
      #pragma unroll
      for (int p = 0; p < 3; ++p) {
        v4f fj[K];
        #pragma unroll
        for (int k = 0; k < K; ++k) fj[k] = *(const v4f*)&s_feat[nb[k]][4 * p];
        #pragma unroll
        for (int q = 0; q < 4; ++q) {
          v2f w = *(const v2f*)&s_w1[12 + 4 * p + q][2 * tt];
          #pragma unroll
          for (int k = 0; k < K; ++k) {
            float fv = getq(fj[k], q);
            a01[k] = pkfma((v2f){fv, fv}, w, a01[k]);
          }
        }
      }
      { // rel_dist channel
        v2f w = *(const v2f*)&s_w1[24][2 * tt];
        #pragma unroll
        for (int k = 0; k < K; ++k)
          a01[k] = pkfma((v2f){rdv[k], rdv[k]}, w, a01[k]);
      }
      if (t < 25) {
        #pragma unroll
        for (int k = 0; k < K; ++k)
          *(float2*)&s_h1[g][k][2 * t] = make_float2(siluf_(a01[k].x), siluf_(a01[k].y));
      }

      // layer-2 (packed even/odd partial sums per edge; reassociation-safe)
      v2f acc2[K];
      #pragma unroll
      for (int k = 0; k < K; ++k) acc2[k] = (v2f){b2v, 0.0f};
      #pragma unroll
      for (int hv = 0; hv < 12; ++hv) {
        v2f wa = *(const v2f*)&s_w2p[2 * hv][2 * t];
        v2f wb = *(const v2f*)&s_w2p[2 * hv + 1][2 * t];
        #pragma unroll
        for (int k = 0; k < K; ++k) {
          v4f h = *(const v4f*)&s_h1[g][k][4 * hv];
          acc2[k] = pkfma(__builtin_shufflevector(h, h, 0, 1), wa, acc2[k]);
          acc2[k] = pkfma(__builtin_shufflevector(h, h, 2, 3), wb, acc2[k]);
        }
      }
      { // tail h = 48,49
        v2f wt = *(const v2f*)&s_w2p[24][2 * t];
        #pragma unroll
        for (int k = 0; k < K; ++k) {
          v2f ht = *(const v2f*)&s_h1[g][k][48];
          acc2[k] = pkfma(ht, wt, acc2[k]);
        }
      }
      float mc[K];
      #pragma unroll
      for (int k = 0; k < K; ++k) mc[k] = siluf_(acc2[k].x + acc2[k].y);

      // soft edge gate + in-register scatter-sum (node owned by this group)
      float acc = 0.0f;
      #pragma unroll
      for (int k = 0; k < K; ++k) {
        float p2 = mc[k] * gwr;
        #pragma unroll
        for (int off = 16; off > 0; off >>= 1) p2 += __shfl_xor(p2, off, 32);
        acc = fmaf(mc[k], sigmoidf_(p2 + gbr), acc);
      }
      s_mi[i][t] = acc;     // plain store: exactly one group writes node i
    }
  }
  __syncthreads();   // h1 dead; union becomes nh1/nout

  // ---- node MLP (+ residual) ----
  for (int u = tid; u < N * NHID; u += 256) {
    int i = u / NHID, o = u - i * NHID;
    float a = s_nb1[o];
    #pragma unroll
    for (int c = 0; c < D; ++c) a = fmaf(s_feat[i][c], s_nw1[c][o], a);
    #pragma unroll
    for (int c = 0; c < M; ++c) a = fmaf(s_mi[i][c], s_nw1[D + c][o], a);
    s_nh1[i][o] = siluf_(a);
  }
  __syncthreads();
  for (int u = tid; u < N * D; u += 256) {
    int i = u / D, o = u - i * D;
    float a = s_nb2[o];
    #pragma unroll
    for (int h = 0; h < NHID; ++h) a = fmaf(s_nh1[i][h], s_nw2[h][o], a);
    s_nout[i][o] = a + s_feat[i][o];
  }
  __syncthreads();   // nh1 dead; tail region (u_buf+1044..) free

  // ---- masked mean pool (/29) + LATE head-weight staging (parallel) ----
  if (tid < D) {
    float a = 0.0f;
    for (int i = 0; i < N; ++i) a += s_nout[i][tid];
    s_pool[tid] = a / 29.0f;
  }
  for (int i = tid; i < D * HHID; i += 256) s_hw1[i / HHID][i % HHID] = hw1[i];
  for (int i = tid; i < HHID; i += 256) s_hb1[i] = hb1[i];
  for (int i = tid; i < HHID * ODIM; i += 256) s_hw2[i / ODIM][i % ODIM] = hw2[i];
  for (int i = tid; i < ODIM; i += 256) s_hb2[i] = hb2[i];
  __syncthreads();

  // ---- head MLP ----
  if (tid < HHID) {
    float a = s_hb1[tid];
    #pragma unroll
    for (int c = 0; c < D; ++c) a = fmaf(s_pool[c], s_hw1[c][tid], a);
    s_hid[tid] = fmaxf(a, 0.0f);
  }
  __syncthreads();
  if (tid < ODIM) {
    float a = s_hb2[tid];
    #pragma unroll
    for (int h = 0; h < HHID; ++h) a = fmaf(s_hid[h], s_hw2[h][tid], a);
    s_res[tid] = a;
  }
  __syncthreads();

  // ---- write [29][12]: rows 0..1 = head out, rows 2..28 = zero padding ----
  float* ob = out + (size_t)b * (N * D);
  for (int i = tid; i < N * D; i += 256) ob[i] = (i < ODIM) ? s_res[i] : 0.0f;
}

} // namespace

extern "C" void kernel_launch(void* const* d_in, const int* in_sizes, int n_in,
                              void* d_out, int out_size, void* d_ws, size_t ws_size,
                              hipStream_t stream) {
  const float* x   = (const float*)d_in[0];
  const float* ctx = (const float*)d_in[1];
  // d_in[2] = mask: constant all-ones in this problem -> mathematically a no-op
  const float* ew1 = (const float*)d_in[3];
  const float* eb1 = (const float*)d_in[4];
  const float* ew2 = (const float*)d_in[5];
  const float* eb2 = (const float*)d_in[6];
  const float* gw  = (const float*)d_in[7];
  const float* gb  = (const float*)d_in[8];
  const float* nw1 = (const float*)d_in[9];
  const float* nb1 = (const float*)d_in[10];
  const float* nw2 = (const float*)d_in[11];
  const float* nb2 = (const float*)d_in[12];
  const float* hw1 = (const float*)d_in[13];
  const float* hb1 = (const float*)d_in[14];
  const float* hw2 = (const float*)d_in[15];
  const float* hb2 = (const float*)d_in[16];
  float* o = (float*)d_out;

  hipLaunchKernelGGL(arnet_fused, dim3(8192), dim3(256), 0, stream,
                     x, ctx, ew1, eb1, ew2, eb2, gw, gb, nw1, nb1, nw2, nb2,
                     hw1, hb1, hw2, hb2, o);
}

// Round 13
// 411.807 us; speedup vs baseline: 1.4563x; 1.0682x over previous
//
#include <hip/hip_runtime.h>

namespace {

constexpr int N = 29;
constexpr int K = 6;
constexpr int D = 12;
constexpr int M = 32;
constexpr int H1 = 50;
constexpr int NHID = 24;    // node hidden = 2*D
constexpr int HHID = 32;    // head hidden
constexpr int ODIM = 24;    // head out = 2*D
constexpr int NITER = 4;    // ceil(29 nodes / 8 groups)

typedef __attribute__((ext_vector_type(2))) float v2f;
typedef __attribute__((ext_vector_type(4))) float v4f;

// fast sigmoid: v_rcp_f32 (<=1 ulp) instead of the ~8-instr precise-div
// sequence; ~100 sigmoids/thread made the div sequence a top VALU consumer.
__device__ __forceinline__ float sigmoidf_(float v) {
  return __builtin_amdgcn_rcpf(1.0f + __expf(-v));
}
__device__ __forceinline__ float siluf_(float v) { return v * sigmoidf_(v); }
__device__ __forceinline__ v2f pkfma(v2f a, v2f b, v2f c) {
  return __builtin_elementwise_fma(a, b, c);     // -> v_pk_fma_f32 (2 FMA/instr)
}
__device__ __forceinline__ float getq(const v4f& f, int q) {
  switch (q) { case 0: return f.x; case 1: return f.y; case 2: return f.z; default: return f.w; }
}

// r12 structure + (a) fast sigmoid, (b) packed node MLP, (c) register-resident
// distance matrix (s_dist eliminated; kNN->edge barrier dropped: neighbor
// lists are produced & consumed by the same wave under identical striping).
__global__ __launch_bounds__(256) void arnet_fused(
    const float* __restrict__ x, const float* __restrict__ ctx,
    const float* __restrict__ ew1, const float* __restrict__ eb1,
    const float* __restrict__ ew2, const float* __restrict__ eb2,
    const float* __restrict__ gw, const float* __restrict__ gb,
    const float* __restrict__ nw1, const float* __restrict__ nb1,
    const float* __restrict__ nw2, const float* __restrict__ nb2,
    const float* __restrict__ hw1, const float* __restrict__ hb1,
    const float* __restrict__ hw2, const float* __restrict__ hb2,
    float* __restrict__ out)
{
  // edge-MLP weights (LDS-resident, conflict-benign layouts)
  __shared__ __attribute__((aligned(16))) float s_w1[25][52];   // lane t: float2 at [c][2t]
  __shared__ __attribute__((aligned(16))) float s_b1[52];
  __shared__ __attribute__((aligned(16))) float s_w2p[25][64];  // [u][2t+par] = e_w2[2u+par][t]
  __shared__ float s_b2[M];
  __shared__ float s_gw[M];
  __shared__ float s_gb;
  // node weights
  __shared__ __attribute__((aligned(16))) float s_nw1[D + M][NHID];
  __shared__ __attribute__((aligned(16))) float s_nb1[NHID];
  __shared__ __attribute__((aligned(16))) float s_nw2[NHID][D];
  __shared__ __attribute__((aligned(16))) float s_nb2[D];
  // persistent per-batch state
  __shared__ float s_ctx[N][5];     // stride 5: conflict-free per-lane row reads
  __shared__ __attribute__((aligned(16))) float s_feat[N][D];  // 48B rows
  __shared__ int   s_nbhd[N][K];
  __shared__ float s_rdist[N][K];
  __shared__ float s_mi[N][M];
  // phase-union region (9984 B), barriers separate all uses:
  //   edge: h1[8][6][52] | node: nh1[29][24]+nout[29][12] | tail: head W+pool
  __shared__ __attribute__((aligned(16))) float u_buf[2496];

  float (*s_h1)[K][52]  = (float(*)[K][52])u_buf;
  float (*s_nh1)[NHID]  = (float(*)[NHID])u_buf;
  float (*s_nout)[D]    = (float(*)[D])(u_buf + 696);
  float (*s_hw1)[HHID]  = (float(*)[HHID])(u_buf + 1044);
  float *s_hb1          = u_buf + 1428;
  float (*s_hw2)[ODIM]  = (float(*)[ODIM])(u_buf + 1460);
  float *s_hb2          = u_buf + 2228;
  float *s_pool         = u_buf + 2252;
  float *s_hid          = u_buf + 2264;
  float *s_res          = u_buf + 2296;

  const int tid = threadIdx.x;
  const int b = blockIdx.x;
  const int g = tid >> 5, t = tid & 31;
  const int tt = (t < 25) ? t : 24;    // clamp for layer-1 reads (lanes 25..31 dup)

  // ---- stage edge-MLP weights ----
  for (int i = tid; i < 25 * H1; i += 256) s_w1[i / H1][i % H1] = ew1[i];
  for (int i = tid; i < H1; i += 256) s_b1[i] = eb1[i];
  for (int i = tid; i < 25 * 64; i += 256) {
    int u = i >> 6, c = i & 63, tc = c >> 1, par = c & 1;
    s_w2p[u][c] = ew2[(2 * u + par) * M + tc];
  }
  for (int i = tid; i < M; i += 256) { s_b2[i] = eb2[i]; s_gw[i] = gw[i]; }
  if (tid == 0) s_gb = gb[0];

  // ---- stage node weights ----
  for (int i = tid; i < (D + M) * NHID; i += 256) s_nw1[i / NHID][i % NHID] = nw1[i];
  for (int i = tid; i < NHID; i += 256) s_nb1[i] = nb1[i];
  for (int i = tid; i < NHID * D; i += 256) s_nw2[i / D][i % D] = nw2[i];
  for (int i = tid; i < D; i += 256) s_nb2[i] = nb2[i];

  // ---- stage per-batch inputs ----
  for (int i = tid; i < N * D; i += 256) {
    int r = i / D, c = i - r * D;
    s_feat[r][c] = x[(size_t)b * (N * 6) + r * 6 + (c % 6)];   // feats = concat([x,x])
  }
  for (int i = tid; i < N * 3; i += 256)
    s_ctx[i / 3][i % 3] = ctx[(size_t)b * (N * 3) + i];
  __syncthreads();

  // ---- kNN with register-resident distances; tie -> lower index ----
  for (int r = g; r < N; r += 8) {
    float v = 3.4e38f;
    if (t < N) {
      float dx = s_ctx[r][0] - s_ctx[t][0];
      float dy = s_ctx[r][1] - s_ctx[t][1];
      float dz = s_ctx[r][2] - s_ctx[t][2];
      v = dx * dx + dy * dy + dz * dz;
    }
    const int myj = t;
    #pragma unroll 1
    for (int k = 0; k < K; ++k) {
      float bv = v; int bi = myj;
      #pragma unroll
      for (int off = 16; off > 0; off >>= 1) {
        float ov = __shfl_xor(bv, off, 32);
        int oi = __shfl_xor(bi, off, 32);
        if (ov < bv || (ov == bv && oi < bi)) { bv = ov; bi = oi; }
      }
      if (t == 0) { s_nbhd[r][k] = bi; s_rdist[r][k] = bv; }
      if (myj == bi) v = 3.4e38f;
    }
  }
  // NO barrier: edge phase group g reads only rows r === g (mod 8), which this
  // same wave just wrote (groups 2w,2w+1 share wave w); lgkmcnt orders it.

  // ---- edge phase: group g owns node i = it*8+g; its 6 edges together ----
  const v2f b1p = *(const v2f*)&s_b1[2 * tt];
  const float b2v = s_b2[t];
  const float gwr = s_gw[t];
  const float gbr = s_gb;

  #pragma unroll 1
  for (int it2 = 0; it2 < NITER; ++it2) {
    const int i = it2 * 8 + g;
    if (i < N) {
      int nb[K]; float rdv[K];
      #pragma unroll
      for (int k = 0; k < K; ++k) { nb[k] = s_nbhd[i][k]; rdv[k] = s_rdist[i][k]; }

      // layer-1, feats_i half (packed): (hidden 2t, hidden 2t+1)
      v2f pa = b1p;
      #pragma unroll
      for (int p = 0; p < 3; ++p) {
        v4f f = *(const v4f*)&s_feat[i][4 * p];
        #pragma unroll
        for (int q = 0; q < 4; ++q) {
          v2f w = *(const v2f*)&s_w1[4 * p + q][2 * tt];
          float fv = getq(f, q);
          pa = pkfma((v2f){fv, fv}, w, pa);
        }
      }
      v2f a01[K];
      #pragma unroll
      for (int k = 0; k < K; ++k) a01[k] = pa;

      // layer-1, feats_j half: per-edge (packed)
      #pragma unroll
      for (int p = 0; p < 3; ++p) {
        v4f fj[K];
        #pragma unroll
        for (int k = 0; k < K; ++k) fj[k] = *(const v4f*)&s_feat[nb[k]][4 * p];
        #pragma unroll
        for (int q = 0; q < 4; ++q) {
          v2f w = *(const v2f*)&s_w1[12 + 4 * p + q][2 * tt];
          #pragma unroll
          for (int k = 0; k < K; ++k) {
            float fv = getq(fj[k], q);
            a01[k] = pkfma((v2f){fv, fv}, w, a01[k]);
          }
        }
      }
      { // rel_dist channel
        v2f w = *(const v2f*)&s_w1[24][2 * tt];
        #pragma unroll
        for (int k = 0; k < K; ++k)
          a01[k] = pkfma((v2f){rdv[k], rdv[k]}, w, a01[k]);
      }
      if (t < 25) {
        #pragma unroll
        for (int k = 0; k < K; ++k)
          *(float2*)&s_h1[g][k][2 * t] = make_float2(siluf_(a01[k].x), siluf_(a01[k].y));
      }

      // layer-2 (packed even/odd partial sums per edge)
      v2f acc2[K];
      #pragma unroll
      for (int k = 0; k < K; ++k) acc2[k] = (v2f){b2v, 0.0f};
      #pragma unroll
      for (int hv = 0; hv < 12; ++hv) {
        v2f wa = *(const v2f*)&s_w2p[2 * hv][2 * t];
        v2f wb = *(const v2f*)&s_w2p[2 * hv + 1][2 * t];
        #pragma unroll
        for (int k = 0; k < K; ++k) {
          v4f h = *(const v4f*)&s_h1[g][k][4 * hv];
          acc2[k] = pkfma(__builtin_shufflevector(h, h, 0, 1), wa, acc2[k]);
          acc2[k] = pkfma(__builtin_shufflevector(h, h, 2, 3), wb, acc2[k]);
        }
      }
      { // tail h = 48,49
        v2f wt = *(const v2f*)&s_w2p[24][2 * t];
        #pragma unroll
        for (int k = 0; k < K; ++k) {
          v2f ht = *(const v2f*)&s_h1[g][k][48];
          acc2[k] = pkfma(ht, wt, acc2[k]);
        }
      }
      float mc[K];
      #pragma unroll
      for (int k = 0; k < K; ++k) mc[k] = siluf_(acc2[k].x + acc2[k].y);

      // soft edge gate + in-register scatter-sum
      float acc = 0.0f;
      #pragma unroll
      for (int k = 0; k < K; ++k) {
        float p2 = mc[k] * gwr;
        #pragma unroll
        for (int off = 16; off > 0; off >>= 1) p2 += __shfl_xor(p2, off, 32);
        acc = fmaf(mc[k], sigmoidf_(p2 + gbr), acc);
      }
      s_mi[i][t] = acc;     // plain store: exactly one group writes node i
    }
  }
  __syncthreads();   // h1 dead; union becomes nh1/nout

  // ---- node MLP (+ residual), packed pairs ----
  for (int up = tid; up < N * 12; up += 256) {
    int i = up / 12, op = up - i * 12;            // output pair (2op, 2op+1)
    v2f a = *(const v2f*)&s_nb1[2 * op];
    #pragma unroll
    for (int c = 0; c < D; ++c) {
      float fv = s_feat[i][c];
      a = pkfma((v2f){fv, fv}, *(const v2f*)&s_nw1[c][2 * op], a);
    }
    #pragma unroll
    for (int c = 0; c < M; ++c) {
      float mv = s_mi[i][c];
      a = pkfma((v2f){mv, mv}, *(const v2f*)&s_nw1[D + c][2 * op], a);
    }
    *(float2*)&s_nh1[i][2 * op] = make_float2(siluf_(a.x), siluf_(a.y));
  }
  __syncthreads();
  if (tid < N * 6) {
    int i = tid / 6, op = tid - i * 6;            // output pair (2op, 2op+1)
    v2f a = *(const v2f*)&s_nb2[2 * op];
    #pragma unroll
    for (int h = 0; h < NHID; ++h) {
      float hv2 = s_nh1[i][h];
      a = pkfma((v2f){hv2, hv2}, *(const v2f*)&s_nw2[h][2 * op], a);
    }
    v2f f = *(const v2f*)&s_feat[i][2 * op];
    a += f;                                        // residual
    *(float2*)&s_nout[i][2 * op] = make_float2(a.x, a.y);
  }
  __syncthreads();   // nh1 dead; tail region (u_buf+1044..) free

  // ---- masked mean pool (/29) + LATE head-weight staging (parallel) ----
  if (tid < D) {
    float a = 0.0f;
    for (int i = 0; i < N; ++i) a += s_nout[i][tid];
    s_pool[tid] = a / 29.0f;
  }
  for (int i = tid; i < D * HHID; i += 256) s_hw1[i / HHID][i % HHID] = hw1[i];
  for (int i = tid; i < HHID; i += 256) s_hb1[i] = hb1[i];
  for (int i = tid; i < HHID * ODIM; i += 256) s_hw2[i / ODIM][i % ODIM] = hw2[i];
  for (int i = tid; i < ODIM; i += 256) s_hb2[i] = hb2[i];
  __syncthreads();

  // ---- head MLP ----
  if (tid < HHID) {
    float a = s_hb1[tid];
    #pragma unroll
    for (int c = 0; c < D; ++c) a = fmaf(s_pool[c], s_hw1[c][tid], a);
    s_hid[tid] = fmaxf(a, 0.0f);
  }
  __syncthreads();
  if (tid < ODIM) {
    float a = s_hb2[tid];
    #pragma unroll
    for (int h = 0; h < HHID; ++h) a = fmaf(s_hid[h], s_hw2[h][tid], a);
    s_res[tid] = a;
  }
  __syncthreads();

  // ---- write [29][12]: rows 0..1 = head out, rows 2..28 = zero padding ----
  float* ob = out + (size_t)b * (N * D);
  for (int i = tid; i < N * D; i += 256) ob[i] = (i < ODIM) ? s_res[i] : 0.0f;
}

} // namespace

extern "C" void kernel_launch(void* const* d_in, const int* in_sizes, int n_in,
                              void* d_out, int out_size, void* d_ws, size_t ws_size,
                              hipStream_t stream) {
  const float* x   = (const float*)d_in[0];
  const float* ctx = (const float*)d_in[1];
  // d_in[2] = mask: constant all-ones in this problem -> mathematically a no-op
  const float* ew1 = (const float*)d_in[3];
  const float* eb1 = (const float*)d_in[4];
  const float* ew2 = (const float*)d_in[5];
  const float* eb2 = (const float*)d_in[6];
  const float* gw  = (const float*)d_in[7];
  const float* gb  = (const float*)d_in[8];
  const float* nw1 = (const float*)d_in[9];
  const float* nb1 = (const float*)d_in[10];
  const float* nw2 = (const float*)d_in[11];
  const float* nb2 = (const float*)d_in[12];
  const float* hw1 = (const float*)d_in[13];
  const float* hb1 = (const float*)d_in[14];
  const float* hw2 = (const float*)d_in[15];
  const float* hb2 = (const float*)d_in[16];
  float* o = (float*)d_out;

  hipLaunchKernelGGL(arnet_fused, dim3(8192), dim3(256), 0, stream,
                     x, ctx, ew1, eb1, ew2, eb2, gw, gb, nw1, nb1, nw2, nb2,
                     hw1, hb1, hw2, hb2, o);
}